// Round 18
// baseline (108.664 us; speedup 1.0000x reference)
//
#include <hip/hip_runtime.h>

#define NB   32
#define NCI  128
#define NH   64
#define NW   64
#define NCO  256
#define NOH  62
#define NOW  62

typedef __attribute__((ext_vector_type(8))) short bf16x8;           // 8 bf16 (4 VGPRs)
typedef __attribute__((ext_vector_type(8))) unsigned short u16x8;
typedef __attribute__((ext_vector_type(4))) float f32x4;

// fp32 -> bf16 bits, round-to-nearest-even (finite inputs)
__device__ __forceinline__ unsigned short f2bf(float f) {
  unsigned int u = __float_as_uint(f);
  u = u + 0x7FFFu + ((u >> 16) & 1u);
  return (unsigned short)(u >> 16);
}

// W[co][ci][kh][kw] fp32 -> wt2[tap][cic][co][oct][8] bf16: per-(tap,cic)
// 16 KB panel in which one wave's af-fragment load is a dense, fully
// coalesced 1024 B window (L1/L2-resident; no LDS staging needed).
__global__ __launch_bounds__(256) void cvt_w_kernel(const float* __restrict__ wsrc,
                                                    unsigned short* __restrict__ wt2) {
  int t = blockIdx.x * 256 + threadIdx.x;      // 0 .. 9*4*256*4 - 1 = 36863
  int oct = t & 3, cic = (t >> 2) & 3, co = (t >> 4) & 255, tap = t >> 12;
  const float* src = wsrc + ((size_t)(co * 128 + cic * 32 + oct * 8)) * 9 + tap;
  u16x8 v;
  #pragma unroll
  for (int j = 0; j < 8; ++j) v[j] = f2bf(src[j * 9]);
  *(u16x8*)(wt2 + (((size_t)(tap * 4 + cic) * 256 + co) * 4 + oct) * 8) = v;
}

// Implicit direct conv, bf16 MFMA 16x16x32 — WEIGHTS-IN-REGISTERS schedule.
// R8-R17 measured wall = LDS + MFMA (sum): 96 ds_read_b128/CU-window (64 af
// + 32 bf) on the shared LDS port + per-tap barriers (ws staged
// cooperatively -> cross-wave LDS dependency) phase-lock all 8 waves. Fix:
// ws LDS is ELIMINATED. af fragments load global->VGPR from wt2 (dense
// 1024B per-wave windows, 8 KB/tap panel: L1-resident, L2 holds all 576 KB),
// prefetched 1 tap deep into an afA/afB register ping-pong. LDS keeps only
// xs (R14's exact 0-conflict layout): ~32 reads+writes per CU-window.
// Barriers drop 36 -> 4 (chunk boundaries only); within a chunk waves
// free-run and the MFMA pipes arbitrate the 2 blocks/SIMD (m114 overlap).
// vmcnt: TOP vmcnt(8) retires af(t) [issued t-1], keeps xs(t-1) flying;
// END vmcnt(8) retires xs(t-1) for the fused xwrite, keeps af(t+1) flying.
// Block: 256 thr (4 waves wn 0..3), tile 128 cout x 4 oh x 64 ow; wave tile
// 128co x 64pix (8m x 4n, 16x16x32 maps verified R14). 36 taps t = c*9+t9.
// LDS 48 KB: xs 2 x [6r][64w][4oct][8] (24 KB, parity c&1).
// xs pipeline: xload8(c+1, uu=t9) at tap END for t9 in {0..5} (c<3);
// xwrite8 at NEXT tap's END (unit (t-1)%9), after vmcnt retires the loads.
// Chunk c+1 writes land taps 9c+1..6; boundary barrier after tap 9c+8;
// chunk c+1 first read (bfC for tap 9c+9) AFTER that barrier. WAR: parity
// (c+1)&1 buffer's old data (chunk c-1) last read at end of tap 9c-1, one
// boundary barrier before the first overwrite at tap 9c+1 END.
// xs w-overreads (w<=65) stay in-allocation, feed masked ow>=62 only.
__global__ __launch_bounds__(256, 2) void conv_mfma_kernel(
    const float* __restrict__ x, const unsigned short* __restrict__ wt2,
    const float* __restrict__ bias, float* __restrict__ out) {
  __shared__ unsigned short smem[24576];   // 49152 B: xs only

  const int tid  = threadIdx.x;
  const int lane = tid & 63;
  const int wid  = tid >> 6;    // 0..3
  const int wn   = wid;         // output row within quad (0..3)
  const int l15  = lane & 15;
  const int lo   = lane >> 4;   // k-octet group

  // XCD-bijective swizzle: grid 1024 = 8 * 128 exactly.
  const int bid0  = blockIdx.x;
  const int bid   = (bid0 & 7) * 128 + (bid0 >> 3);
  const int coutg = bid & 1;               // ((b*16 + ohg)*2 + coutg)
  const int ohg   = (bid >> 1) & 15;
  const int b     = bid >> 5;
  const int cbase = coutg * 128;
  const int oh0   = ohg * 4;               // 0..60 (ohg 15: rows 62,63 masked)

  f32x4 acc[8][4];
  #pragma unroll
  for (int mi = 0; mi < 8; ++mi)
    #pragma unroll
    for (int ni = 0; ni < 4; ++ni)
      acc[mi][ni] = (f32x4){0.f, 0.f, 0.f, 0.f};

  const char* sm = (const char*)smem;
  const char* wb = (const char*)wt2;
  // af per-lane byte offset within a (tap,cic) panel: dense 1024B window
  const int alo = (cbase + l15) * 64 + lo * 16;

  // x fp32 base for this batch image
  const float* xb = x + ((size_t)b * NCI) * (NH * NW);

  // af global->reg: 8 x global_load_dwordx4, dense coalesced
  auto load_af = [&](bf16x8 (&dst)[8], int t) {
    const char* p = wb + (size_t)((t % 9) * 4 + t / 9) * 16384 + alo;
    #pragma unroll
    for (int mi = 0; mi < 8; ++mi)
      dst[mi] = *(const bf16x8*)(p + mi * 1024);
  };

  // bf from xs LDS (R14 layout + swizzle, 0 conflicts measured)
  auto read_bf = [&](bf16x8 (&dst)[4], int t) {
    const int t9 = t % 9, cn = t / 9;
    const int kh = t9 / 3, kw = t9 - kh * 3;
    const char* xsp = sm + (cn & 1) * 24576 + (wn + kh) * 4096;
    const int w9 = l15 + kw;
    const int bfl = w9 * 64 + ((lo ^ ((w9 >> 1) & 3)) << 4);
    #pragma unroll
    for (int ni = 0; ni < 4; ++ni)
      dst[ni] = *(const bf16x8*)(xsp + ni * 1024 + bfl);
  };

  // fused x staging: unit uu of chunk c1 = (row r, ci-octet oct, w = lane)
  auto xload8 = [&](int c1, int uu, float (&xf)[8]) {
    const int g = uu * 4 + wid;            // 0..23
    const int r = g % 6, oct = g / 6;
    int row = oh0 + r; if (row > 63) row = 63;       // clamp (masked outputs)
    const float* src = xb + (size_t)(c1 * 32 + oct * 8) * (NH * NW)
                     + row * NW + lane;
    #pragma unroll
    for (int j = 0; j < 8; ++j) xf[j] = src[(size_t)j * (NH * NW)];
  };
  auto xwrite8 = [&](int c1, int uu, float (&xf)[8]) {
    const int g = uu * 4 + wid;
    const int r = g % 6, oct = g / 6;
    u16x8 v;
    #pragma unroll
    for (int j = 0; j < 8; ++j) v[j] = f2bf(xf[j]);
    *(u16x8*)(smem + (c1 & 1) * 12288 +
              ((r * 64 + lane) * 4 + (oct ^ ((lane >> 1) & 3))) * 8) = v;
  };

  bf16x8 afA[8], afB[8], bfC[4];
  float xf[8];

  // one tap; afU = this tap's A-frags (landed), afN = next tap's dest regs
  auto tap_body = [&](bf16x8 (&afU)[8], bf16x8 (&afN)[8], int t) {
    const int t9 = t % 9, c = t / 9;
    const bool xsPrev = (t >= 1) && ((t - 1) % 9 <= 5) && ((t - 1) / 9 < 3);
    const bool xsCur  = (t9 <= 5) && (c < 3);

    // TOP: retire af(t) (older than xs(t-1)? no: FIFO [af(t)@t-1 top,
    // xs(t-1)@t-1 end] -> af older); keep xs(t-1) in flight.
    if (xsPrev) { asm volatile("s_waitcnt vmcnt(8)" ::: "memory"); }
    else        { asm volatile("s_waitcnt vmcnt(0)" ::: "memory"); }
    asm volatile("s_waitcnt lgkmcnt(0)" ::: "memory");   // bfC landed
    __builtin_amdgcn_sched_barrier(0);

    if (t < 35) load_af(afN, t + 1);       // flies across the whole tap
    __builtin_amdgcn_sched_barrier(0);

    __builtin_amdgcn_s_setprio(1);
    #pragma unroll
    for (int mi = 0; mi < 8; ++mi)
      #pragma unroll
      for (int ni = 0; ni < 4; ++ni)
        acc[mi][ni] = __builtin_amdgcn_mfma_f32_16x16x32_bf16(
            afU[mi], bfC[ni], acc[mi][ni], 0, 0, 0);
    __builtin_amdgcn_s_setprio(0);

    // bfC for t+1 (single-buffered; after last use). Boundary: after barrier.
    if (t < 35 && (t + 1) % 9 != 0) read_bf(bfC, t + 1);

    // END: retire xs(t-1) (oldest), keep af(t+1); fused cvt+write; new xload
    if (xsPrev) {
      if (t < 35) { asm volatile("s_waitcnt vmcnt(8)" ::: "memory"); }
      else        { asm volatile("s_waitcnt vmcnt(0)" ::: "memory"); }
      xwrite8((t - 1) / 9 + 1, (t - 1) % 9, xf);
    }
    if (xsCur) xload8(c + 1, t9, xf);

    if (t9 == 8 && c < 3) {                // chunk boundary: 3 barriers total
      asm volatile("s_waitcnt lgkmcnt(0)" ::: "memory");  // flush xwrites
      __builtin_amdgcn_s_barrier();
      __builtin_amdgcn_sched_barrier(0);
      read_bf(bfC, t + 1);                 // first read of chunk c+1
    }
  };

  // prologue: chunk 0 (fused transpose), af(0); one barrier
  {
    float x6[6][8];
    #pragma unroll
    for (int u = 0; u < 6; ++u) xload8(0, u, x6[u]);
    load_af(afA, 0);
    asm volatile("s_waitcnt vmcnt(8)" ::: "memory");      // x48 retired
    #pragma unroll
    for (int u = 0; u < 6; ++u) xwrite8(0, u, x6[u]);
    asm volatile("s_waitcnt vmcnt(0) lgkmcnt(0)" ::: "memory");
    __builtin_amdgcn_s_barrier();
    __builtin_amdgcn_sched_barrier(0);
    read_bf(bfC, 0);
  }

  for (int h = 0; h < 18; ++h) {           // afA/afB parity static per slot
    tap_body(afA, afB, 2 * h);
    tap_body(afB, afA, 2 * h + 1);
  }

  // epilogue: D row = lo*4 + reg (cout), col = l15 (ow)  [R14-verified]
  const int oh = oh0 + wn;
  if (oh < NOH) {
    #pragma unroll
    for (int mi = 0; mi < 8; ++mi) {
      int co0 = cbase + mi * 16 + lo * 4;
      const f32x4 bv = *(const f32x4*)(bias + co0);
      #pragma unroll
      for (int ni = 0; ni < 4; ++ni) {
        int ow = ni * 16 + l15;
        if (ow < NOW) {
          size_t o0 = (((size_t)b * NCO + co0) * NOH + oh) * NOW + ow;
          const size_t cs = (size_t)NOH * NOW;
          out[o0]          = acc[mi][ni][0] + bv[0];
          out[o0 + cs]     = acc[mi][ni][1] + bv[1];
          out[o0 + 2 * cs] = acc[mi][ni][2] + bv[2];
          out[o0 + 3 * cs] = acc[mi][ni][3] + bv[3];
        }
      }
    }
  }
}

// Safety-net: correct fp32 direct conv (used only if ws_size too small)
__global__ __launch_bounds__(256) void conv_naive_kernel(
    const float* __restrict__ x, const float* __restrict__ w,
    const float* __restrict__ bias, float* __restrict__ out) {
  long t = (long)blockIdx.x * 256 + threadIdx.x;
  const long total = (long)NB * NCO * NOH * NOW;
  if (t >= total) return;
  int ow = (int)(t % NOW);
  int oh = (int)((t / NOW) % NOH);
  int co = (int)((t / ((long)NOW * NOH)) % NCO);
  int b  = (int)(t / ((long)NOW * NOH * NCO));
  float acc = bias[co];
  for (int ci = 0; ci < NCI; ++ci) {
    const float* xp = x + (((size_t)b * NCI + ci) * NH + oh) * NW + ow;
    const float* wp = w + ((size_t)co * NCI + ci) * 9;
    #pragma unroll
    for (int kh = 0; kh < 3; ++kh)
      #pragma unroll
      for (int kw = 0; kw < 3; ++kw)
        acc += xp[kh * NW + kw] * wp[kh * 3 + kw];
  }
  out[t] = acc;
}

extern "C" void kernel_launch(void* const* d_in, const int* in_sizes, int n_in,
                              void* d_out, int out_size, void* d_ws, size_t ws_size,
                              hipStream_t stream) {
  const float* x    = (const float*)d_in[0];
  const float* w    = (const float*)d_in[1];
  const float* bias = (const float*)d_in[2];
  float* out        = (float*)d_out;

  const size_t WT_BYTES = (size_t)9 * 4 * NCO * 4 * 8 * 2;       // 589824

  if (ws_size >= WT_BYTES) {
    unsigned short* wt2 = (unsigned short*)d_ws;
    cvt_w_kernel<<<144, 256, 0, stream>>>(w, wt2);
    conv_mfma_kernel<<<2 * 16 * NB, 256, 0, stream>>>(x, wt2, bias, out);
  } else {
    const long total = (long)NB * NCO * NOH * NOW;
    conv_naive_kernel<<<(int)((total + 255) / 256), 256, 0, stream>>>(x, w, bias, out);
  }
}

// Round 19
// 86.649 us; speedup vs baseline: 1.2541x; 1.2541x over previous
//
#include <hip/hip_runtime.h>

#define NB   32
#define NCI  128
#define NH   64
#define NW   64
#define NCO  256
#define NOH  62
#define NOW  62

typedef __attribute__((ext_vector_type(8))) short bf16x8;           // 8 bf16 (4 VGPRs)
typedef __attribute__((ext_vector_type(8))) unsigned short u16x8;
typedef __attribute__((ext_vector_type(4))) float f32x4;

typedef __attribute__((address_space(1))) const unsigned int glb_u32_t;
typedef __attribute__((address_space(3))) unsigned int lds_u32_t;

// fp32 -> bf16 bits, round-to-nearest-even (finite inputs)
__device__ __forceinline__ unsigned short f2bf(float f) {
  unsigned int u = __float_as_uint(f);
  u = u + 0x7FFFu + ((u >> 16) & 1u);
  return (unsigned short)(u >> 16);
}

__device__ __forceinline__ void gload_lds16(const unsigned short* g, unsigned short* l) {
  __builtin_amdgcn_global_load_lds((glb_u32_t*)g, (lds_u32_t*)l, 16, 0, 0);
}

// W[co][ci][kh][kw] fp32 -> wt[k][co][ci] bf16, coalesced 16B stores
__global__ __launch_bounds__(256) void cvt_w_kernel(const float* __restrict__ wsrc,
                                                    unsigned short* __restrict__ wt) {
  int t = blockIdx.x * 256 + threadIdx.x;            // 0 .. 9*256*16-1
  int oc = t & 15, co = (t >> 4) & 255, k = t >> 12;
  const float* src = wsrc + ((size_t)co * NCI + oc * 8) * 9 + k;
  u16x8 v;
  #pragma unroll
  for (int j = 0; j < 8; ++j) v[j] = f2bf(src[j * 9]);
  *(u16x8*)(wt + ((size_t)k * NCO + co) * NCI + oc * 8) = v;
}

// Implicit direct conv, bf16 MFMA 16x16x32 — R14 (best: fused x transpose
// staging, half-tap pipeline, 0 bank conflicts) + bfC/bfD PING-PONG restored
// (R13's pattern). R14 had dropped bfD to fund xf[8], leaving bf(t+1)
// single-buffered at the tap end -> exposed LDS latency at every tap-top
// lgkmcnt(0). Budget recheck: af 32 + bfC/bfD 32 + xf 8 + addr ~30 = 102
// vector regs <= 128 (acc owns the other 128 as AGPR) -> it fits. R5/R12/R18
// triply confirmed weights must flow via global_load_lds + ds_read, not
// global->VGPR.
// Block: 256 thr (4 waves wn 0..3), tile 128 cout x 4 oh x 64 ow; wave tile
// 128co x 64pix (8m x 4n). 36 taps t = c*9 + t9. LDS 80 KB (2 blocks/CU):
//   xs: 2 x [6r][64w][4oct][8] (24 KB, parity c&1)  bytes [0, 49152)
//   ws: 4 x [128co][4oct][8]   (8 KB, slot t&3)     bytes [49152, 81920)
// Per tap: {x8 loads (t9 in 2..7); stage_w(t+3)} then
//   half0: 16 MFMA (afX x bfc)  || read afY = af[4:7](t)        (4 ds_read)
//   half1: 16 MFMA (afY x bfc)  || read afX(t+1) + bfn(t+1)     (8 ds_read)
// tap end: vmcnt(2) [retires ws(t+2)+x8, keeps ws(t+3)]; fused xwrite;
// lgkmcnt(0) on staging taps; s_barrier.
// Hazards (walked): ws ring-4 WAR -- stage_w(t+3) writes (t-1)&3, whose last
// reads (afY half0 of t-1 / afX-prefetch half1 of t-2) complete before each
// wave's own lgkm at t-1, which precedes its end-of-(t-1) barrier; stage_w
// issues after that barrier. xs: chunk c+1 units written at ends of taps
// 9c+2..9c+7 (each followed by lgkm(0)+barrier); first cross-chunk read is
// bfn for tap 9c+9 during half1 of tap 9c+8 -- one barrier after the last
// write. Same-tap parity collision impossible (xst false at t9==8). xs WAR:
// chunk c-1's last read (bfn for 9c-1, half1 of 9c-2) is 4 barriers before
// chunk c+1's first overwrite (end of 9c+2).
// xs w-overreads (w<=65) stay in-allocation, feed masked ow>=62 only.
__global__ __launch_bounds__(256, 2) void conv_mfma_kernel(
    const float* __restrict__ x, const unsigned short* __restrict__ wt,
    const float* __restrict__ bias, float* __restrict__ out) {
  __shared__ unsigned short smem[40960];   // 81920 B

  const int tid  = threadIdx.x;
  const int lane = tid & 63;
  const int wid  = tid >> 6;    // 0..3
  const int wn   = wid;         // output row within quad (0..3)
  const int l15  = lane & 15;
  const int lo   = lane >> 4;   // k-octet group

  // XCD-bijective swizzle: grid 1024 = 8 * 128 exactly.
  const int bid0  = blockIdx.x;
  const int bid   = (bid0 & 7) * 128 + (bid0 >> 3);
  const int coutg = bid & 1;               // ((b*16 + ohg)*2 + coutg)
  const int ohg   = (bid >> 1) & 15;
  const int b     = bid >> 5;
  const int cbase = coutg * 128;
  const int oh0   = ohg * 4;               // 0..60 (ohg 15: rows 62,63 masked)

  f32x4 acc[8][4];
  #pragma unroll
  for (int mi = 0; mi < 8; ++mi)
    #pragma unroll
    for (int ni = 0; ni < 4; ++ni)
      acc[mi][ni] = (f32x4){0.f, 0.f, 0.f, 0.f};

  // per-lane LDS read base (bytes); mi/ni terms are static offsets
  const char* sm = (const char*)smem;
  const int af_lane = l15 * 64 + ((lo ^ ((l15 >> 1) & 3)) << 4);

  // x fp32 base for this batch image
  const float* xb = x + ((size_t)b * NCI) * (NH * NW);

  const unsigned short* wsrc2[2];
  #pragma unroll
  for (int i = 0; i < 2; ++i) {
    int e = (wid * 2 + i) * 64 + lane;     // 0..511
    int o = e & 3, co = e >> 2;            // co 0..127
    wsrc2[i] = wt + (size_t)(cbase + co) * NCI + ((o ^ ((co >> 1) & 3)) * 8);
  }

  // stage ws for global tap t into slot t&3: 2 gload/thread
  auto stage_w = [&](int t) {
    unsigned short* dst = smem + 24576 + (t & 3) * 4096;
    const size_t so = (size_t)(t % 9) * NCO * NCI + (t / 9) * 32;
    #pragma unroll
    for (int i = 0; i < 2; ++i)
      gload_lds16(wsrc2[i] + so, dst + ((wid * 2 + i) * 64 + lane) * 8);
  };

  // fused x staging: unit uu of chunk c1 = (row r, ci-octet oct, w = lane)
  auto xload8 = [&](int c1, int uu, float (&xf)[8]) {
    const int g = uu * 4 + wid;            // 0..23
    const int r = g % 6, oct = g / 6;
    int row = oh0 + r; if (row > 63) row = 63;       // clamp (masked outputs)
    const float* src = xb + (size_t)(c1 * 32 + oct * 8) * (NH * NW)
                     + row * NW + lane;
    #pragma unroll
    for (int j = 0; j < 8; ++j) xf[j] = src[(size_t)j * (NH * NW)];
  };
  auto xwrite8 = [&](int c1, int uu, float (&xf)[8]) {
    const int g = uu * 4 + wid;
    const int r = g % 6, oct = g / 6;
    u16x8 v;
    #pragma unroll
    for (int j = 0; j < 8; ++j) v[j] = f2bf(xf[j]);
    *(u16x8*)(smem + (c1 & 1) * 12288 +
              ((r * 64 + lane) * 4 + (oct ^ ((lane >> 1) & 3))) * 8) = v;
  };

  bf16x8 afX[4], afY[4], bfC[4], bfD[4];

  // one tap body; bfc = this tap's B-frags (landed), bfn = next tap's
  // (filled by half1's interleaved reads when pf).
  auto tap_body = [&](int t, bf16x8 (&bfc)[4], bf16x8 (&bfn)[4], bool pf) {
    const int t9 = t % 9, c = t / 9;
    const bool xst = (t9 >= 2 && t9 <= 7) && (c < 3);
    float xf[8];

    // ---- tap top: x unit loads (oldest), then ws stage (stays in flight)
    if (xst) xload8(c + 1, t9 - 2, xf);
    __builtin_amdgcn_sched_barrier(0);
    if (t + 3 < 36) stage_w(t + 3);
    __builtin_amdgcn_sched_barrier(0);

    const char* wsp  = sm + 49152 + (t & 3) * 8192;        // this tap's ws
    const char* wspn = sm + 49152 + ((t + 1) & 3) * 8192;  // next tap's ws
    const int tn = t + 1, tn9 = tn % 9, cn = tn / 9;
    const int khn = tn9 / 3, kwn = tn9 - khn * 3;
    const char* xspn = sm + (cn & 1) * 24576 + (wn + khn) * 4096;
    const int w9n = l15 + kwn;
    const int bfln = w9n * 64 + ((lo ^ ((w9n >> 1) & 3)) << 4);

    // ---- half 0: acc[0..3] += afX x bfc  ||  afY <- af[4:7](t)
    asm volatile("s_waitcnt lgkmcnt(0)" ::: "memory");
    __builtin_amdgcn_sched_barrier(0);
    __builtin_amdgcn_s_setprio(1);
    #pragma unroll
    for (int ni = 0; ni < 4; ++ni)
      acc[0][ni] = __builtin_amdgcn_mfma_f32_16x16x32_bf16(afX[0], bfc[ni], acc[0][ni], 0, 0, 0);
    afY[0] = *(const bf16x8*)(wsp + 4 * 1024 + af_lane);
    afY[1] = *(const bf16x8*)(wsp + 5 * 1024 + af_lane);
    #pragma unroll
    for (int ni = 0; ni < 4; ++ni)
      acc[1][ni] = __builtin_amdgcn_mfma_f32_16x16x32_bf16(afX[1], bfc[ni], acc[1][ni], 0, 0, 0);
    afY[2] = *(const bf16x8*)(wsp + 6 * 1024 + af_lane);
    afY[3] = *(const bf16x8*)(wsp + 7 * 1024 + af_lane);
    #pragma unroll
    for (int ni = 0; ni < 4; ++ni)
      acc[2][ni] = __builtin_amdgcn_mfma_f32_16x16x32_bf16(afX[2], bfc[ni], acc[2][ni], 0, 0, 0);
    #pragma unroll
    for (int ni = 0; ni < 4; ++ni)
      acc[3][ni] = __builtin_amdgcn_mfma_f32_16x16x32_bf16(afX[3], bfc[ni], acc[3][ni], 0, 0, 0);
    __builtin_amdgcn_s_setprio(0);

    // ---- half 1: acc[4..7] += afY x bfc  ||  afX,bfn <- tap t+1
    asm volatile("s_waitcnt lgkmcnt(0)" ::: "memory");
    __builtin_amdgcn_sched_barrier(0);
    __builtin_amdgcn_s_setprio(1);
    #pragma unroll
    for (int ni = 0; ni < 4; ++ni)
      acc[4][ni] = __builtin_amdgcn_mfma_f32_16x16x32_bf16(afY[0], bfc[ni], acc[4][ni], 0, 0, 0);
    if (pf) {
      afX[0] = *(const bf16x8*)(wspn + 0 * 1024 + af_lane);
      afX[1] = *(const bf16x8*)(wspn + 1 * 1024 + af_lane);
    }
    #pragma unroll
    for (int ni = 0; ni < 4; ++ni)
      acc[5][ni] = __builtin_amdgcn_mfma_f32_16x16x32_bf16(afY[1], bfc[ni], acc[5][ni], 0, 0, 0);
    if (pf) {
      afX[2] = *(const bf16x8*)(wspn + 2 * 1024 + af_lane);
      afX[3] = *(const bf16x8*)(wspn + 3 * 1024 + af_lane);
    }
    #pragma unroll
    for (int ni = 0; ni < 4; ++ni)
      acc[6][ni] = __builtin_amdgcn_mfma_f32_16x16x32_bf16(afY[2], bfc[ni], acc[6][ni], 0, 0, 0);
    if (pf) {
      #pragma unroll
      for (int i = 0; i < 4; ++i)
        bfn[i] = *(const bf16x8*)(xspn + i * 1024 + bfln);
    }
    #pragma unroll
    for (int ni = 0; ni < 4; ++ni)
      acc[7][ni] = __builtin_amdgcn_mfma_f32_16x16x32_bf16(afY[3], bfc[ni], acc[7][ni], 0, 0, 0);
    __builtin_amdgcn_s_setprio(0);

    // ---- tap end: counted vmcnt; fused x cvt+write; barrier
    if (t >= 33) {
      asm volatile("s_waitcnt vmcnt(0)" ::: "memory");
    } else {
      asm volatile("s_waitcnt vmcnt(2)" ::: "memory");   // retires ws(t+2)+x8
    }
    if (xst) {
      xwrite8(c + 1, t9 - 2, xf);
      asm volatile("s_waitcnt lgkmcnt(0)" ::: "memory"); // flush ds_writes
    }
    __builtin_amdgcn_s_barrier();
    __builtin_amdgcn_sched_barrier(0);
  };

  // prologue: chunk 0 (fused transpose), ws slots 0,1,2; drain; frag fill
  {
    float xa[8], xbv[8], xc[8], xd[8], xe[8], xg[8];
    xload8(0, 0, xa); xload8(0, 1, xbv); xload8(0, 2, xc);
    xload8(0, 3, xd); xload8(0, 4, xe);  xload8(0, 5, xg);
    stage_w(0); stage_w(1); stage_w(2);
    asm volatile("s_waitcnt vmcnt(6)" ::: "memory");   // x48 retired
    xwrite8(0, 0, xa); xwrite8(0, 1, xbv); xwrite8(0, 2, xc);
    xwrite8(0, 3, xd); xwrite8(0, 4, xe);  xwrite8(0, 5, xg);
    asm volatile("s_waitcnt vmcnt(0) lgkmcnt(0)" ::: "memory");
    __builtin_amdgcn_s_barrier();
    __builtin_amdgcn_sched_barrier(0);
    const char* wsp0 = sm + 49152;
    #pragma unroll
    for (int i = 0; i < 4; ++i)
      afX[i] = *(const bf16x8*)(wsp0 + i * 1024 + af_lane);
    const char* xsp0 = sm + wn * 4096;     // t=0: c=0, kh=0, kw=0
    #pragma unroll
    for (int i = 0; i < 4; ++i)            // kw=0: bfl == af_lane formula
      bfC[i] = *(const bf16x8*)(xsp0 + i * 1024 + af_lane);
  }

  for (int j = 0; j < 9; ++j) {
    const int t0 = 4 * j;
    tap_body(t0 + 0, bfC, bfD, true);
    tap_body(t0 + 1, bfD, bfC, true);
    tap_body(t0 + 2, bfC, bfD, true);
    tap_body(t0 + 3, bfD, bfC, j < 8);
  }

  // epilogue: D row = lo*4 + reg (cout), col = l15 (ow)
  const int oh = oh0 + wn;
  if (oh < NOH) {
    #pragma unroll
    for (int mi = 0; mi < 8; ++mi) {
      int co0 = cbase + mi * 16 + lo * 4;
      const f32x4 bv = *(const f32x4*)(bias + co0);
      #pragma unroll
      for (int ni = 0; ni < 4; ++ni) {
        int ow = ni * 16 + l15;
        if (ow < NOW) {
          size_t o0 = (((size_t)b * NCO + co0) * NOH + oh) * NOW + ow;
          const size_t cs = (size_t)NOH * NOW;
          out[o0]          = acc[mi][ni][0] + bv[0];
          out[o0 + cs]     = acc[mi][ni][1] + bv[1];
          out[o0 + 2 * cs] = acc[mi][ni][2] + bv[2];
          out[o0 + 3 * cs] = acc[mi][ni][3] + bv[3];
        }
      }
    }
  }
}

// Safety-net: correct fp32 direct conv (used only if ws_size too small)
__global__ __launch_bounds__(256) void conv_naive_kernel(
    const float* __restrict__ x, const float* __restrict__ w,
    const float* __restrict__ bias, float* __restrict__ out) {
  long t = (long)blockIdx.x * 256 + threadIdx.x;
  const long total = (long)NB * NCO * NOH * NOW;
  if (t >= total) return;
  int ow = (int)(t % NOW);
  int oh = (int)((t / NOW) % NOH);
  int co = (int)((t / ((long)NOW * NOH)) % NCO);
  int b  = (int)(t / ((long)NOW * NOH * NCO));
  float acc = bias[co];
  for (int ci = 0; ci < NCI; ++ci) {
    const float* xp = x + (((size_t)b * NCI + ci) * NH + oh) * NW + ow;
    const float* wp = w + ((size_t)co * NCI + ci) * 9;
    #pragma unroll
    for (int kh = 0; kh < 3; ++kh)
      #pragma unroll
      for (int kw = 0; kw < 3; ++kw)
        acc += xp[kh * NW + kw] * wp[kh * 3 + kw];
  }
  out[t] = acc;
}

extern "C" void kernel_launch(void* const* d_in, const int* in_sizes, int n_in,
                              void* d_out, int out_size, void* d_ws, size_t ws_size,
                              hipStream_t stream) {
  const float* x    = (const float*)d_in[0];
  const float* w    = (const float*)d_in[1];
  const float* bias = (const float*)d_in[2];
  float* out        = (float*)d_out;

  const size_t WT_BYTES = (size_t)9 * NCO * NCI * 2;             // 589824

  if (ws_size >= WT_BYTES) {
    unsigned short* wt = (unsigned short*)d_ws;
    cvt_w_kernel<<<(9 * NCO * 16) / 256, 256, 0, stream>>>(w, wt);
    conv_mfma_kernel<<<2 * 16 * NB, 256, 0, stream>>>(x, wt, bias, out);
  } else {
    const long total = (long)NB * NCO * NOH * NOW;
    conv_naive_kernel<<<(int)((total + 255) / 256), 256, 0, stream>>>(x, w, bias, out);
  }
}